// Round 1
// baseline (679.016 us; speedup 1.0000x reference)
//
#include <hip/hip_runtime.h>

#define N_NODES 50000
#define N_EDGES 800000
#define M_EDGES (N_EDGES + N_NODES)
#define F_IN 56
#define F_PAD 64
#define F_OUT 256
#define FB 32

// ---- CSR build ------------------------------------------------------------

__global__ void k_count(const int* __restrict__ ei, int* __restrict__ cnt) {
  int e = blockIdx.x * blockDim.x + threadIdx.x;
  if (e < N_EDGES) atomicAdd(&cnt[ei[N_EDGES + e]], 1);
}

__global__ void k_dinv(const int* __restrict__ cnt, float* __restrict__ dinv) {
  int i = blockIdx.x * blockDim.x + threadIdx.x;
  if (i < N_NODES) dinv[i] = rsqrtf((float)(cnt[i] + 1));  // +1 self loop; deg>=1
}

__global__ void k_scan(const int* __restrict__ cnt, int* __restrict__ rp) {
  __shared__ int sums[1024];
  const int n = N_NODES;
  const int C = (n + 1023) >> 10;
  int t = threadIdx.x;
  int beg = t * C, end = min(beg + C, n);
  int s = 0;
  for (int i = beg; i < end; ++i) s += cnt[i] + 1;  // +1 for self loop slot
  sums[t] = s;
  __syncthreads();
  for (int off = 1; off < 1024; off <<= 1) {
    int u = (t >= off) ? sums[t - off] : 0;
    __syncthreads();
    sums[t] += u;
    __syncthreads();
  }
  int run = sums[t] - s;  // exclusive prefix
  for (int i = beg; i < end; ++i) { rp[i] = run; run += cnt[i] + 1; }
  if (end == n) rp[n] = run;  // all writers (incl. empty chunks) write M_EDGES
}

__global__ void k_fill(const int* __restrict__ ei, const float* __restrict__ dinv,
                       const int* __restrict__ rp, int* __restrict__ cursor,
                       int2* __restrict__ edges) {
  int e = blockIdx.x * blockDim.x + threadIdx.x;
  if (e >= N_EDGES) return;
  int s = ei[e];
  int d = ei[N_EDGES + e];
  int pos = atomicAdd(&cursor[d], 1);
  edges[rp[d] + pos] = make_int2(s, __float_as_int(dinv[s] * dinv[d]));
}

__global__ void k_self(const float* __restrict__ dinv, const int* __restrict__ rp,
                       int2* __restrict__ edges) {
  int i = blockIdx.x * blockDim.x + threadIdx.x;
  if (i >= N_NODES) return;
  float di = dinv[i];
  edges[rp[i + 1] - 1] = make_int2(i, __float_as_int(di * di));  // last slot = self loop
}

// ---- feature init: x padded to 64 cols, ones-vector in col 56 -------------

__global__ void k_loadx(const float* __restrict__ x, float* __restrict__ h) {
  int i = blockIdx.x * blockDim.x + threadIdx.x;  // N*64 threads
  int nn = i >> 6, f = i & 63;
  float v = 0.f;
  if (f < F_IN) v = x[nn * F_IN + f];
  else if (f == F_IN) v = 1.f;
  h[i] = v;
}

// ---- one hop: wave per node, gather over CSR row --------------------------

__global__ __launch_bounds__(256) void k_hop(const float* __restrict__ hin,
                                             float* __restrict__ hout,
                                             const int* __restrict__ rp,
                                             const int2* __restrict__ edges,
                                             float* __restrict__ vsave) {
  int wv = (blockIdx.x * blockDim.x + threadIdx.x) >> 6;  // node id
  int lane = threadIdx.x & 63;
  int beg = rp[wv], end = rp[wv + 1];
  float acc = 0.f;
  int e = beg;
  for (; e + 2 <= end; e += 2) {
    int2 e0 = edges[e], e1 = edges[e + 1];
    float a0 = hin[(size_t)e0.x * F_PAD + lane];
    float a1 = hin[(size_t)e1.x * F_PAD + lane];
    acc = fmaf(__int_as_float(e0.y), a0, acc);
    acc = fmaf(__int_as_float(e1.y), a1, acc);
  }
  if (e < end) {
    int2 e0 = edges[e];
    acc = fmaf(__int_as_float(e0.y), hin[(size_t)e0.x * F_PAD + lane], acc);
  }
  hout[(size_t)wv * F_PAD + lane] = acc;
  if (vsave != nullptr && lane == F_IN) vsave[wv] = acc;  // snapshot Â^k·1
}

// ---- collapse weights: M = W1W2W3W4; c1=b1'W2W3W4; c2=b2'W3W4; c3=b3'W4+b4

__global__ void k_weights(const float* __restrict__ W1, const float* __restrict__ b1,
                          const float* __restrict__ W2, const float* __restrict__ b2,
                          const float* __restrict__ W3, const float* __restrict__ b3,
                          const float* __restrict__ W4, const float* __restrict__ b4,
                          float* __restrict__ Mw, float* __restrict__ c1,
                          float* __restrict__ c2, float* __restrict__ c3) {
  __shared__ float t1[64], t2[64], t3[64];
  int m = blockIdx.x, tid = threadIdx.x;
  if (m < F_IN) {  // row m of M: ((W1[m,:]W2)W3)W4
    if (tid < 64) {
      float a = 0.f;
      for (int k = 0; k < 64; ++k) a = fmaf(W1[m * 64 + k], W2[k * 64 + tid], a);
      t1[tid] = a;
    }
    __syncthreads();
    if (tid < 64) {
      float a = 0.f;
      for (int k = 0; k < 64; ++k) a = fmaf(t1[k], W3[k * 64 + tid], a);
      t2[tid] = a;
    }
    __syncthreads();
    {
      float a = 0.f;
      for (int k = 0; k < 64; ++k) a = fmaf(t2[k], W4[k * 256 + tid], a);
      Mw[m * 256 + tid] = a;
    }
  } else {  // bias chains
    if (tid < 64) {
      float a = 0.f;
      for (int k = 0; k < 64; ++k) a = fmaf(b1[k], W2[k * 64 + tid], a);
      t1[tid] = a;
    }
    __syncthreads();
    if (tid < 64) {
      float a = 0.f, b = 0.f;
      for (int k = 0; k < 64; ++k) {
        float w3 = W3[k * 64 + tid];
        a = fmaf(t1[k], w3, a);
        b = fmaf(b2[k], w3, b);
      }
      t2[tid] = a; t3[tid] = b;
    }
    __syncthreads();
    {
      float a = 0.f, b = 0.f, c = 0.f;
      for (int k = 0; k < 64; ++k) {
        float w4 = W4[k * 256 + tid];
        a = fmaf(t2[k], w4, a);
        b = fmaf(t3[k], w4, b);
        c = fmaf(b3[k], w4, c);
      }
      c1[tid] = a; c2[tid] = b; c3[tid] = c + b4[tid];
    }
  }
}

// ---- epilogue: out = y@M + v6*c1 + v3*c2 + c3 -----------------------------

__global__ __launch_bounds__(256) void k_final(const float* __restrict__ y,
                                               const float* __restrict__ v3,
                                               const float* __restrict__ v6,
                                               const float* __restrict__ Mw,
                                               const float* __restrict__ c1,
                                               const float* __restrict__ c2,
                                               const float* __restrict__ c3,
                                               float* __restrict__ out) {
  __shared__ float Ml[F_IN * F_OUT];       // 56 KiB
  __shared__ float yl[FB][F_IN];
  __shared__ float v3l[FB], v6l[FB];
  int tid = threadIdx.x;
  for (int i = tid; i < F_IN * F_OUT; i += 256) Ml[i] = Mw[i];
  int n0 = blockIdx.x * FB;
  int lim = min(FB, N_NODES - n0);
  if (tid < FB) { v3l[tid] = 0.f; v6l[tid] = 0.f; }
  __syncthreads();
  for (int i = tid; i < lim * F_IN; i += 256) {
    int nn = i / F_IN, k = i - nn * F_IN;
    yl[nn][k] = y[(size_t)(n0 + nn) * F_PAD + k];
  }
  if (tid < lim) { v3l[tid] = v3[n0 + tid]; v6l[tid] = v6[n0 + tid]; }
  __syncthreads();
  int j = tid;
  float C1 = c1[j], C2 = c2[j], C3 = c3[j];
  float acc[FB];
#pragma unroll
  for (int nn = 0; nn < FB; ++nn) acc[nn] = fmaf(v6l[nn], C1, fmaf(v3l[nn], C2, C3));
  for (int k = 0; k < F_IN; ++k) {
    float mk = Ml[k * F_OUT + j];
#pragma unroll
    for (int nn = 0; nn < FB; ++nn) acc[nn] = fmaf(yl[nn][k], mk, acc[nn]);
  }
  for (int nn = 0; nn < lim; ++nn) out[(size_t)(n0 + nn) * F_OUT + j] = acc[nn];
}

// ---- launch ---------------------------------------------------------------

extern "C" void kernel_launch(void* const* d_in, const int* in_sizes, int n_in,
                              void* d_out, int out_size, void* d_ws, size_t ws_size,
                              hipStream_t stream) {
  const float* x  = (const float*)d_in[0];
  const int*   ei = (const int*)d_in[1];
  const float* W1 = (const float*)d_in[2];
  const float* b1 = (const float*)d_in[3];
  const float* W2 = (const float*)d_in[4];
  const float* b2 = (const float*)d_in[5];
  const float* W3 = (const float*)d_in[6];
  const float* b3 = (const float*)d_in[7];
  const float* W4 = (const float*)d_in[8];
  const float* b4 = (const float*)d_in[9];
  float* out = (float*)d_out;

  char* ws = (char*)d_ws;
  size_t off = 0;
  auto take = [&](size_t bytes) -> void* {
    void* p = ws + off;
    off += (bytes + 255) & ~(size_t)255;
    return p;
  };
  int*   cnt   = (int*)take((size_t)N_NODES * 4);
  int*   rp    = (int*)take((size_t)(N_NODES + 1) * 4);
  float* dinv  = (float*)take((size_t)N_NODES * 4);
  float* v3    = (float*)take((size_t)N_NODES * 4);
  float* v6    = (float*)take((size_t)N_NODES * 4);
  int2*  edges = (int2*)take((size_t)M_EDGES * 8);
  float* hA    = (float*)take((size_t)N_NODES * F_PAD * 4);
  float* hB    = (float*)take((size_t)N_NODES * F_PAD * 4);
  float* Mw    = (float*)take((size_t)F_IN * F_OUT * 4);
  float* c1    = (float*)take((size_t)F_OUT * 4);
  float* c2    = (float*)take((size_t)F_OUT * 4);
  float* c3    = (float*)take((size_t)F_OUT * 4);

  hipMemsetAsync(cnt, 0, (size_t)N_NODES * 4, stream);
  k_count<<<(N_EDGES + 255) / 256, 256, 0, stream>>>(ei, cnt);
  k_dinv<<<(N_NODES + 255) / 256, 256, 0, stream>>>(cnt, dinv);
  k_scan<<<1, 1024, 0, stream>>>(cnt, rp);
  hipMemsetAsync(cnt, 0, (size_t)N_NODES * 4, stream);
  k_fill<<<(N_EDGES + 255) / 256, 256, 0, stream>>>(ei, dinv, rp, cnt, edges);
  k_self<<<(N_NODES + 255) / 256, 256, 0, stream>>>(dinv, rp, edges);
  k_loadx<<<(N_NODES * F_PAD) / 256, 256, 0, stream>>>(x, hA);
  k_weights<<<F_IN + 1, 256, 0, stream>>>(W1, b1, W2, b2, W3, b3, W4, b4, Mw, c1, c2, c3);

  float* src = hA;
  float* dst = hB;
  for (int hop = 1; hop <= 9; ++hop) {
    float* vs = (hop == 3) ? v3 : (hop == 6) ? v6 : nullptr;
    k_hop<<<(N_NODES * 64) / 256, 256, 0, stream>>>(src, dst, rp, edges, vs);
    float* t = src; src = dst; dst = t;
  }
  k_final<<<(N_NODES + FB - 1) / FB, 256, 0, stream>>>(src, v3, v6, Mw, c1, c2, c3, out);
}

// Round 2
// 447.084 us; speedup vs baseline: 1.5188x; 1.5188x over previous
//
#include <hip/hip_runtime.h>

#define N_NODES 50000
#define N_EDGES 800000
#define F_IN 56
#define F_PAD 64
#define F_OUT 256
#define FB 32
#define ELL_W 64   // max (deg+1) per node; Poisson(16) max ~36, huge margin

// ---- degree count ---------------------------------------------------------

__global__ void k_count(const int* __restrict__ ei, int* __restrict__ cnt) {
  int e = blockIdx.x * blockDim.x + threadIdx.x;
  if (e < N_EDGES) atomicAdd(&cnt[ei[N_EDGES + e]], 1);
}

// ---- dinv + deg + self-loop slot + cursor init (fused) --------------------

__global__ void k_dinv(const int* __restrict__ cnt, float* __restrict__ dinv,
                       int* __restrict__ deg, int* __restrict__ ell,
                       int* __restrict__ cursor) {
  int i = blockIdx.x * blockDim.x + threadIdx.x;
  if (i >= N_NODES) return;
  int c = cnt[i];
  dinv[i] = rsqrtf((float)(c + 1));
  deg[i] = c + 1;
  ell[(i << 6) + c] = i;  // self loop in last used slot
  cursor[i] = 0;
}

// ---- ELL fill: slot = node<<6 + cursor ------------------------------------

__global__ void k_fill(const int* __restrict__ ei, int* __restrict__ cursor,
                       int* __restrict__ ell) {
  int e = blockIdx.x * blockDim.x + threadIdx.x;
  if (e >= N_EDGES) return;
  int s = ei[e];
  int d = ei[N_EDGES + e];
  int pos = atomicAdd(&cursor[d], 1);
  ell[(d << 6) + pos] = s;
}

// ---- feature init: x padded to 64 cols, ones-vector in col 56 -------------

__global__ void k_loadx(const float* __restrict__ x, float* __restrict__ h) {
  int i = blockIdx.x * blockDim.x + threadIdx.x;  // N*64 threads
  int nn = i >> 6, f = i & 63;
  float v = 0.f;
  if (f < F_IN) v = x[nn * F_IN + f];
  else if (f == F_IN) v = 1.f;
  h[i] = v;
}

// ---- one hop: wave per node, readlane-broadcast gather --------------------

__global__ __launch_bounds__(256) void k_hop(const float* __restrict__ hin,
                                             float* __restrict__ hout,
                                             const int* __restrict__ deg,
                                             const int* __restrict__ ell,
                                             const float* __restrict__ dinv,
                                             float* __restrict__ vsave) {
  int node = (blockIdx.x * blockDim.x + threadIdx.x) >> 6;
  int lane = threadIdx.x & 63;
  int d = __builtin_amdgcn_readfirstlane(deg[node]);
  int rec = ell[((size_t)node << 6) + lane];   // one coalesced 256B row load
  rec = (lane < d) ? rec : node;               // sanitize unused slots
  float wl = dinv[rec] * dinv[node];           // per-lane edge weight (self loop = dinv^2)
  int wbits = __float_as_int(wl);
  float acc = 0.f;
  int j = 0;
  for (; j + 4 <= d; j += 4) {
    int s0 = __builtin_amdgcn_readlane(rec, j);
    int s1 = __builtin_amdgcn_readlane(rec, j + 1);
    int s2 = __builtin_amdgcn_readlane(rec, j + 2);
    int s3 = __builtin_amdgcn_readlane(rec, j + 3);
    float w0 = __int_as_float(__builtin_amdgcn_readlane(wbits, j));
    float w1 = __int_as_float(__builtin_amdgcn_readlane(wbits, j + 1));
    float w2 = __int_as_float(__builtin_amdgcn_readlane(wbits, j + 2));
    float w3 = __int_as_float(__builtin_amdgcn_readlane(wbits, j + 3));
    float a0 = hin[((size_t)s0 << 6) + lane];
    float a1 = hin[((size_t)s1 << 6) + lane];
    float a2 = hin[((size_t)s2 << 6) + lane];
    float a3 = hin[((size_t)s3 << 6) + lane];
    acc = fmaf(w0, a0, acc);
    acc = fmaf(w1, a1, acc);
    acc = fmaf(w2, a2, acc);
    acc = fmaf(w3, a3, acc);
  }
  for (; j < d; ++j) {
    int s0 = __builtin_amdgcn_readlane(rec, j);
    float w0 = __int_as_float(__builtin_amdgcn_readlane(wbits, j));
    acc = fmaf(w0, hin[((size_t)s0 << 6) + lane], acc);
  }
  hout[((size_t)node << 6) + lane] = acc;
  if (vsave != nullptr && lane == F_IN) vsave[node] = acc;  // snapshot A^k·1
}

// ---- collapse weights: M = W1W2W3W4; c1=b1'W2W3W4; c2=b2'W3W4; c3=b3'W4+b4

__global__ void k_weights(const float* __restrict__ W1, const float* __restrict__ b1,
                          const float* __restrict__ W2, const float* __restrict__ b2,
                          const float* __restrict__ W3, const float* __restrict__ b3,
                          const float* __restrict__ W4, const float* __restrict__ b4,
                          float* __restrict__ Mw, float* __restrict__ c1,
                          float* __restrict__ c2, float* __restrict__ c3) {
  __shared__ float t1[64], t2[64], t3[64];
  int m = blockIdx.x, tid = threadIdx.x;
  if (m < F_IN) {  // row m of M: ((W1[m,:]W2)W3)W4
    if (tid < 64) {
      float a = 0.f;
      for (int k = 0; k < 64; ++k) a = fmaf(W1[m * 64 + k], W2[k * 64 + tid], a);
      t1[tid] = a;
    }
    __syncthreads();
    if (tid < 64) {
      float a = 0.f;
      for (int k = 0; k < 64; ++k) a = fmaf(t1[k], W3[k * 64 + tid], a);
      t2[tid] = a;
    }
    __syncthreads();
    {
      float a = 0.f;
      for (int k = 0; k < 64; ++k) a = fmaf(t2[k], W4[k * 256 + tid], a);
      Mw[m * 256 + tid] = a;
    }
  } else {  // bias chains
    if (tid < 64) {
      float a = 0.f;
      for (int k = 0; k < 64; ++k) a = fmaf(b1[k], W2[k * 64 + tid], a);
      t1[tid] = a;
    }
    __syncthreads();
    if (tid < 64) {
      float a = 0.f, b = 0.f;
      for (int k = 0; k < 64; ++k) {
        float w3 = W3[k * 64 + tid];
        a = fmaf(t1[k], w3, a);
        b = fmaf(b2[k], w3, b);
      }
      t2[tid] = a; t3[tid] = b;
    }
    __syncthreads();
    {
      float a = 0.f, b = 0.f, c = 0.f;
      for (int k = 0; k < 64; ++k) {
        float w4 = W4[k * 256 + tid];
        a = fmaf(t2[k], w4, a);
        b = fmaf(t3[k], w4, b);
        c = fmaf(b3[k], w4, c);
      }
      c1[tid] = a; c2[tid] = b; c3[tid] = c + b4[tid];
    }
  }
}

// ---- epilogue: out = y@M + v6*c1 + v3*c2 + c3 -----------------------------

__global__ __launch_bounds__(256) void k_final(const float* __restrict__ y,
                                               const float* __restrict__ v3,
                                               const float* __restrict__ v6,
                                               const float* __restrict__ Mw,
                                               const float* __restrict__ c1,
                                               const float* __restrict__ c2,
                                               const float* __restrict__ c3,
                                               float* __restrict__ out) {
  __shared__ float Ml[F_IN * F_OUT];       // 56 KiB
  __shared__ float yl[FB][F_IN];
  __shared__ float v3l[FB], v6l[FB];
  int tid = threadIdx.x;
  for (int i = tid; i < F_IN * F_OUT; i += 256) Ml[i] = Mw[i];
  int n0 = blockIdx.x * FB;
  int lim = min(FB, N_NODES - n0);
  if (tid < FB) { v3l[tid] = 0.f; v6l[tid] = 0.f; }
  __syncthreads();
  for (int i = tid; i < lim * F_IN; i += 256) {
    int nn = i / F_IN, k = i - nn * F_IN;
    yl[nn][k] = y[(size_t)(n0 + nn) * F_PAD + k];
  }
  if (tid < lim) { v3l[tid] = v3[n0 + tid]; v6l[tid] = v6[n0 + tid]; }
  __syncthreads();
  int j = tid;
  float C1 = c1[j], C2 = c2[j], C3 = c3[j];
  float acc[FB];
#pragma unroll
  for (int nn = 0; nn < FB; ++nn) acc[nn] = fmaf(v6l[nn], C1, fmaf(v3l[nn], C2, C3));
  for (int k = 0; k < F_IN; ++k) {
    float mk = Ml[k * F_OUT + j];
#pragma unroll
    for (int nn = 0; nn < FB; ++nn) acc[nn] = fmaf(yl[nn][k], mk, acc[nn]);
  }
  for (int nn = 0; nn < lim; ++nn) out[(size_t)(n0 + nn) * F_OUT + j] = acc[nn];
}

// ---- launch ---------------------------------------------------------------

extern "C" void kernel_launch(void* const* d_in, const int* in_sizes, int n_in,
                              void* d_out, int out_size, void* d_ws, size_t ws_size,
                              hipStream_t stream) {
  const float* x  = (const float*)d_in[0];
  const int*   ei = (const int*)d_in[1];
  const float* W1 = (const float*)d_in[2];
  const float* b1 = (const float*)d_in[3];
  const float* W2 = (const float*)d_in[4];
  const float* b2 = (const float*)d_in[5];
  const float* W3 = (const float*)d_in[6];
  const float* b3 = (const float*)d_in[7];
  const float* W4 = (const float*)d_in[8];
  const float* b4 = (const float*)d_in[9];
  float* out = (float*)d_out;

  char* ws = (char*)d_ws;
  size_t off = 0;
  auto take = [&](size_t bytes) -> void* {
    void* p = ws + off;
    off += (bytes + 255) & ~(size_t)255;
    return p;
  };
  int*   cnt    = (int*)take((size_t)N_NODES * 4);
  int*   deg    = (int*)take((size_t)N_NODES * 4);
  int*   cursor = (int*)take((size_t)N_NODES * 4);
  float* dinv   = (float*)take((size_t)N_NODES * 4);
  float* v3     = (float*)take((size_t)N_NODES * 4);
  float* v6     = (float*)take((size_t)N_NODES * 4);
  int*   ell    = (int*)take((size_t)N_NODES * ELL_W * 4);   // 12.8 MB
  float* hA     = (float*)take((size_t)N_NODES * F_PAD * 4); // 12.8 MB
  float* hB     = (float*)take((size_t)N_NODES * F_PAD * 4); // 12.8 MB
  float* Mw     = (float*)take((size_t)F_IN * F_OUT * 4);
  float* c1     = (float*)take((size_t)F_OUT * 4);
  float* c2     = (float*)take((size_t)F_OUT * 4);
  float* c3     = (float*)take((size_t)F_OUT * 4);

  hipMemsetAsync(cnt, 0, (size_t)N_NODES * 4, stream);
  k_count<<<(N_EDGES + 255) / 256, 256, 0, stream>>>(ei, cnt);
  k_dinv<<<(N_NODES + 255) / 256, 256, 0, stream>>>(cnt, dinv, deg, ell, cursor);
  k_fill<<<(N_EDGES + 255) / 256, 256, 0, stream>>>(ei, cursor, ell);
  k_loadx<<<(N_NODES * F_PAD) / 256, 256, 0, stream>>>(x, hA);
  k_weights<<<F_IN + 1, 256, 0, stream>>>(W1, b1, W2, b2, W3, b3, W4, b4, Mw, c1, c2, c3);

  float* src = hA;
  float* dst = hB;
  for (int hop = 1; hop <= 9; ++hop) {
    float* vs = (hop == 3) ? v3 : (hop == 6) ? v6 : nullptr;
    k_hop<<<(N_NODES * F_PAD) / 256, 256, 0, stream>>>(src, dst, deg, ell, dinv, vs);
    float* t = src; src = dst; dst = t;
  }
  k_final<<<(N_NODES + FB - 1) / FB, 256, 0, stream>>>(src, v3, v6, Mw, c1, c2, c3, out);
}

// Round 3
// 427.424 us; speedup vs baseline: 1.5886x; 1.0460x over previous
//
#include <hip/hip_runtime.h>

#define N_NODES 50000
#define N_EDGES 800000
#define F_IN 56
#define F_PAD 64
#define F_OUT 256
#define NB 64      // nodes per k_final block
#define ELL_W 64   // max (deg+1) per node; Poisson(16) max ~36, huge margin

// ---- degree count ---------------------------------------------------------

__global__ void k_count(const int* __restrict__ ei, int* __restrict__ cnt) {
  int e = blockIdx.x * blockDim.x + threadIdx.x;
  if (e < N_EDGES) atomicAdd(&cnt[ei[N_EDGES + e]], 1);
}

// ---- dinv + deg + self-loop slot + cursor init (fused) --------------------

__global__ void k_dinv(const int* __restrict__ cnt, float* __restrict__ dinv,
                       int* __restrict__ deg, int* __restrict__ ell,
                       int* __restrict__ cursor) {
  int i = blockIdx.x * blockDim.x + threadIdx.x;
  if (i >= N_NODES) return;
  int c = cnt[i];
  dinv[i] = rsqrtf((float)(c + 1));
  deg[i] = c + 1;
  ell[(i << 6) + c] = i;  // self loop in last used slot
  cursor[i] = 0;
}

// ---- ELL fill: slot = node<<6 + cursor ------------------------------------

__global__ void k_fill(const int* __restrict__ ei, int* __restrict__ cursor,
                       int* __restrict__ ell) {
  int e = blockIdx.x * blockDim.x + threadIdx.x;
  if (e >= N_EDGES) return;
  int s = ei[e];
  int d = ei[N_EDGES + e];
  int pos = atomicAdd(&cursor[d], 1);
  ell[(d << 6) + pos] = s;
}

// ---- feature init: x padded to 64 cols, ones-vector in col 56 -------------

__global__ void k_loadx(const float* __restrict__ x, float* __restrict__ h) {
  int i = blockIdx.x * blockDim.x + threadIdx.x;  // N*64 threads
  int nn = i >> 6, f = i & 63;
  float v = 0.f;
  if (f < F_IN) v = x[nn * F_IN + f];
  else if (f == F_IN) v = 1.f;
  h[i] = v;
}

// ---- one hop: wave per node, 4 edge-rows per dwordx4 gather ---------------
// lane = (edge subgroup: lane>>4) x (feature quad: (lane&15)*4)

__global__ __launch_bounds__(256) void k_hop(const float* __restrict__ hin,
                                             float* __restrict__ hout,
                                             const int* __restrict__ deg,
                                             const int* __restrict__ ell,
                                             const float* __restrict__ dinv,
                                             float* __restrict__ vsave) {
  int node = (blockIdx.x * blockDim.x + threadIdx.x) >> 6;
  int lane = threadIdx.x & 63;
  int d = __builtin_amdgcn_readfirstlane(deg[node]);  // includes self loop, >=1
  int rec = ell[((size_t)node << 6) + lane];          // one coalesced 256B row load
  rec = (lane < d) ? rec : node;                      // safe address for pad slots
  float dn = __int_as_float(__builtin_amdgcn_readfirstlane(
      __float_as_int(dinv[node])));
  float wl = (lane < d) ? dinv[rec] * dn : 0.f;       // pad slots weight 0

  int sub = lane >> 4;          // which of the 4 edges this lane serves
  int fo  = (lane & 15) << 2;   // feature offset within row (0,4,...,60)
  float4 acc = make_float4(0.f, 0.f, 0.f, 0.f);

  int ngroups = (d + 3) >> 2;   // groups of 4 edges (zero-weight padded)
  int g = 0;
  for (; g + 2 <= ngroups; g += 2) {
    int   s0 = __shfl(rec, g * 4 + sub);
    float w0 = __shfl(wl,  g * 4 + sub);
    int   s1 = __shfl(rec, g * 4 + 4 + sub);
    float w1 = __shfl(wl,  g * 4 + 4 + sub);
    float4 a0 = *(const float4*)(hin + (((size_t)s0) << 6) + fo);
    float4 a1 = *(const float4*)(hin + (((size_t)s1) << 6) + fo);
    acc.x = fmaf(w0, a0.x, acc.x);
    acc.y = fmaf(w0, a0.y, acc.y);
    acc.z = fmaf(w0, a0.z, acc.z);
    acc.w = fmaf(w0, a0.w, acc.w);
    acc.x = fmaf(w1, a1.x, acc.x);
    acc.y = fmaf(w1, a1.y, acc.y);
    acc.z = fmaf(w1, a1.z, acc.z);
    acc.w = fmaf(w1, a1.w, acc.w);
  }
  if (g < ngroups) {
    int   s0 = __shfl(rec, g * 4 + sub);
    float w0 = __shfl(wl,  g * 4 + sub);
    float4 a0 = *(const float4*)(hin + (((size_t)s0) << 6) + fo);
    acc.x = fmaf(w0, a0.x, acc.x);
    acc.y = fmaf(w0, a0.y, acc.y);
    acc.z = fmaf(w0, a0.z, acc.z);
    acc.w = fmaf(w0, a0.w, acc.w);
  }
  // reduce the 4 edge subgroups (lanes l, l^16, l^32, l^48)
  acc.x += __shfl_xor(acc.x, 16);
  acc.y += __shfl_xor(acc.y, 16);
  acc.z += __shfl_xor(acc.z, 16);
  acc.w += __shfl_xor(acc.w, 16);
  acc.x += __shfl_xor(acc.x, 32);
  acc.y += __shfl_xor(acc.y, 32);
  acc.z += __shfl_xor(acc.z, 32);
  acc.w += __shfl_xor(acc.w, 32);

  if (lane < 16) {
    *(float4*)(hout + ((size_t)node << 6) + fo) = acc;
  }
  if (vsave != nullptr && lane == 14) vsave[node] = acc.x;  // feature 56 = A^k·1
}

// ---- collapse weights: M = W1W2W3W4; c1=b1'W2W3W4; c2=b2'W3W4; c3=b3'W4+b4

__global__ void k_weights(const float* __restrict__ W1, const float* __restrict__ b1,
                          const float* __restrict__ W2, const float* __restrict__ b2,
                          const float* __restrict__ W3, const float* __restrict__ b3,
                          const float* __restrict__ W4, const float* __restrict__ b4,
                          float* __restrict__ Mw, float* __restrict__ c1,
                          float* __restrict__ c2, float* __restrict__ c3) {
  __shared__ float t1[64], t2[64], t3[64];
  int m = blockIdx.x, tid = threadIdx.x;
  if (m < F_IN) {  // row m of M: ((W1[m,:]W2)W3)W4
    if (tid < 64) {
      float a = 0.f;
      for (int k = 0; k < 64; ++k) a = fmaf(W1[m * 64 + k], W2[k * 64 + tid], a);
      t1[tid] = a;
    }
    __syncthreads();
    if (tid < 64) {
      float a = 0.f;
      for (int k = 0; k < 64; ++k) a = fmaf(t1[k], W3[k * 64 + tid], a);
      t2[tid] = a;
    }
    __syncthreads();
    {
      float a = 0.f;
      for (int k = 0; k < 64; ++k) a = fmaf(t2[k], W4[k * 256 + tid], a);
      Mw[m * 256 + tid] = a;
    }
  } else {  // bias chains
    if (tid < 64) {
      float a = 0.f;
      for (int k = 0; k < 64; ++k) a = fmaf(b1[k], W2[k * 64 + tid], a);
      t1[tid] = a;
    }
    __syncthreads();
    if (tid < 64) {
      float a = 0.f, b = 0.f;
      for (int k = 0; k < 64; ++k) {
        float w3 = W3[k * 64 + tid];
        a = fmaf(t1[k], w3, a);
        b = fmaf(b2[k], w3, b);
      }
      t2[tid] = a; t3[tid] = b;
    }
    __syncthreads();
    {
      float a = 0.f, b = 0.f, c = 0.f;
      for (int k = 0; k < 64; ++k) {
        float w4 = W4[k * 256 + tid];
        a = fmaf(t2[k], w4, a);
        b = fmaf(t3[k], w4, b);
        c = fmaf(b3[k], w4, c);
      }
      c1[tid] = a; c2[tid] = b; c3[tid] = c + b4[tid];
    }
  }
}

// ---- epilogue: out = y@M + v6*c1 + v3*c2 + c3 -----------------------------
// thread j owns output col j; M[:,j] in 56 registers; y rows broadcast via LDS

__global__ __launch_bounds__(256) void k_final(const float* __restrict__ y,
                                               const float* __restrict__ v3,
                                               const float* __restrict__ v6,
                                               const float* __restrict__ Mw,
                                               const float* __restrict__ c1,
                                               const float* __restrict__ c2,
                                               const float* __restrict__ c3,
                                               float* __restrict__ out) {
  __shared__ float4 yl[NB][16];          // 16.5 KB
  __shared__ float v3l[NB], v6l[NB];
  int tid = threadIdx.x;
  int j = tid;                           // output column

  float4 Mreg[14];                       // M[:, j] — 56 VGPRs
#pragma unroll
  for (int k4 = 0; k4 < 14; ++k4) {
    Mreg[k4].x = Mw[(k4 * 4 + 0) * F_OUT + j];
    Mreg[k4].y = Mw[(k4 * 4 + 1) * F_OUT + j];
    Mreg[k4].z = Mw[(k4 * 4 + 2) * F_OUT + j];
    Mreg[k4].w = Mw[(k4 * 4 + 3) * F_OUT + j];
  }
  float C1 = c1[j], C2 = c2[j], C3 = c3[j];

  int n0 = blockIdx.x * NB;
  int lim = min(NB, N_NODES - n0);
  for (int i = tid; i < lim * 16; i += 256) {
    int nn = i >> 4, q = i & 15;
    yl[nn][q] = *(const float4*)(y + ((size_t)(n0 + nn) << 6) + q * 4);
  }
  if (tid < lim) { v3l[tid] = v3[n0 + tid]; v6l[tid] = v6[n0 + tid]; }
  __syncthreads();

  for (int nn = 0; nn < lim; ++nn) {
    float acc = fmaf(v6l[nn], C1, fmaf(v3l[nn], C2, C3));
#pragma unroll
    for (int k4 = 0; k4 < 14; ++k4) {
      float4 yv = yl[nn][k4];
      acc = fmaf(yv.x, Mreg[k4].x, acc);
      acc = fmaf(yv.y, Mreg[k4].y, acc);
      acc = fmaf(yv.z, Mreg[k4].z, acc);
      acc = fmaf(yv.w, Mreg[k4].w, acc);
    }
    out[(size_t)(n0 + nn) * F_OUT + j] = acc;
  }
}

// ---- launch ---------------------------------------------------------------

extern "C" void kernel_launch(void* const* d_in, const int* in_sizes, int n_in,
                              void* d_out, int out_size, void* d_ws, size_t ws_size,
                              hipStream_t stream) {
  const float* x  = (const float*)d_in[0];
  const int*   ei = (const int*)d_in[1];
  const float* W1 = (const float*)d_in[2];
  const float* b1 = (const float*)d_in[3];
  const float* W2 = (const float*)d_in[4];
  const float* b2 = (const float*)d_in[5];
  const float* W3 = (const float*)d_in[6];
  const float* b3 = (const float*)d_in[7];
  const float* W4 = (const float*)d_in[8];
  const float* b4 = (const float*)d_in[9];
  float* out = (float*)d_out;

  char* ws = (char*)d_ws;
  size_t off = 0;
  auto take = [&](size_t bytes) -> void* {
    void* p = ws + off;
    off += (bytes + 255) & ~(size_t)255;
    return p;
  };
  int*   cnt    = (int*)take((size_t)N_NODES * 4);
  int*   deg    = (int*)take((size_t)N_NODES * 4);
  int*   cursor = (int*)take((size_t)N_NODES * 4);
  float* dinv   = (float*)take((size_t)N_NODES * 4);
  float* v3     = (float*)take((size_t)N_NODES * 4);
  float* v6     = (float*)take((size_t)N_NODES * 4);
  int*   ell    = (int*)take((size_t)N_NODES * ELL_W * 4);   // 12.8 MB
  float* hA     = (float*)take((size_t)N_NODES * F_PAD * 4); // 12.8 MB
  float* hB     = (float*)take((size_t)N_NODES * F_PAD * 4); // 12.8 MB
  float* Mw     = (float*)take((size_t)F_IN * F_OUT * 4);
  float* c1     = (float*)take((size_t)F_OUT * 4);
  float* c2     = (float*)take((size_t)F_OUT * 4);
  float* c3     = (float*)take((size_t)F_OUT * 4);

  hipMemsetAsync(cnt, 0, (size_t)N_NODES * 4, stream);
  k_count<<<(N_EDGES + 255) / 256, 256, 0, stream>>>(ei, cnt);
  k_dinv<<<(N_NODES + 255) / 256, 256, 0, stream>>>(cnt, dinv, deg, ell, cursor);
  k_fill<<<(N_EDGES + 255) / 256, 256, 0, stream>>>(ei, cursor, ell);
  k_loadx<<<(N_NODES * F_PAD) / 256, 256, 0, stream>>>(x, hA);
  k_weights<<<F_IN + 1, 256, 0, stream>>>(W1, b1, W2, b2, W3, b3, W4, b4, Mw, c1, c2, c3);

  float* src = hA;
  float* dst = hB;
  for (int hop = 1; hop <= 9; ++hop) {
    float* vs = (hop == 3) ? v3 : (hop == 6) ? v6 : nullptr;
    k_hop<<<(N_NODES * F_PAD) / 256, 256, 0, stream>>>(src, dst, deg, ell, dinv, vs);
    float* t = src; src = dst; dst = t;
  }
  k_final<<<(N_NODES + NB - 1) / NB, 256, 0, stream>>>(src, v3, v6, Mw, c1, c2, c3, out);
}